// Round 6
// baseline (1211.078 us; speedup 1.0000x reference)
//
#include <hip/hip_runtime.h>

#define N_NODES 100000
#define N_EDGES 3200000
#define N_GRAPHS 1000
#define NB 1024            // dst-range buckets
#define NPB 98             // nodes per bucket (1024*98 >= 100000)
#define CAP 3584           // per-bucket edge capacity (mean 3136 + 8 sigma)
#define EPB 4096           // edges per bucketing block

// ---------------- workspace layout (element offsets, 4B units) --------------
// deg  : int  [N]          @ 0        real in-edge count (self-loop excluded)
// dinv : float[N]          @ N        rsqrt(deg+1)
// xp   : float[4N]         @ 2N       x * dinv (pre-scaled L1 features)
// t2p  : float[32N]        @ 6N       (h1@W2) * dinv
// t3p  : float[16N]        @ 38N      (h2@W3) * dinv
// bcnt : int  [NB]         @ 54N
// gsum : float[G]          @ 54N+NB
// gcnt : int  [G]          @ 54N+NB+G
// pay  : uint [NB*CAP]     @ 54N+NB+2G   packed (src | local_dst<<17)
// total ≈ 9.1M elements ≈ 36.4 MB

__global__ void k_zero(int* __restrict__ deg, int* __restrict__ bcnt,
                       float* __restrict__ gsum, int* __restrict__ gcnt) {
    int i = blockIdx.x * blockDim.x + threadIdx.x;
    if (i < N_NODES) deg[i] = 0;
    if (i < NB) bcnt[i] = 0;
    if (i < N_GRAPHS) { gsum[i] = 0.0f; gcnt[i] = 0; }
}

// two-level bucketize: LDS histogram -> scan -> LDS place -> contiguous run flush
__global__ __launch_bounds__(256) void k_bucket(
    const int* __restrict__ src, const int* __restrict__ dst,
    int* __restrict__ deg, int* __restrict__ bcnt, unsigned* __restrict__ pay) {
    __shared__ int cnt[NB];        // per-bucket count within this block
    __shared__ int off[NB];        // exclusive start -> running cursor
    __shared__ int scanbuf[256];
    __shared__ unsigned rec[EPB];  // records grouped by bucket

    int tid = threadIdx.x;
    int e0 = blockIdx.x * EPB;
    for (int i = tid; i < NB; i += 256) cnt[i] = 0;
    __syncthreads();

    // phase 1: histogram (+ global degree count)
#pragma unroll
    for (int k = 0; k < EPB / 256; ++k) {
        int e = e0 + k * 256 + tid;
        if (e < N_EDGES) {
            unsigned d = (unsigned)dst[e];
            atomicAdd(&deg[d], 1);
            atomicAdd(&cnt[d / NPB], 1);
        }
    }
    __syncthreads();

    // phase 2: exclusive scan of cnt[1024] (thread owns 4 consecutive buckets)
    int base = tid * 4;
    int c0 = cnt[base], c1 = cnt[base + 1], c2 = cnt[base + 2], c3 = cnt[base + 3];
    int part = c0 + c1 + c2 + c3;
    scanbuf[tid] = part;
    __syncthreads();
    for (int o = 1; o < 256; o <<= 1) {
        int v = (tid >= o) ? scanbuf[tid - o] : 0;
        __syncthreads();
        scanbuf[tid] += v;
        __syncthreads();
    }
    int ex = scanbuf[tid] - part;
    off[base]     = ex;
    off[base + 1] = ex + c0;
    off[base + 2] = ex + c0 + c1;
    off[base + 3] = ex + c0 + c1 + c2;
    __syncthreads();

    // phase 3: place records grouped by bucket (re-read edges; L2-hot)
#pragma unroll
    for (int k = 0; k < EPB / 256; ++k) {
        int e = e0 + k * 256 + tid;
        if (e < N_EDGES) {
            unsigned s = (unsigned)src[e];
            unsigned d = (unsigned)dst[e];
            unsigned b = d / NPB;
            unsigned ld = d - b * NPB;
            int p = atomicAdd(&off[b], 1);
            rec[p] = s | (ld << 17);
        }
    }
    __syncthreads();

    // phase 4: flush contiguous runs (one global cursor atomic per run)
    for (int b = tid; b < NB; b += 256) {
        int c = cnt[b];
        if (c == 0) continue;
        int ls = off[b] - c;                       // local start
        int gb = atomicAdd(&bcnt[b], c);           // global base
        unsigned* dstp = pay + (size_t)b * CAP;
        for (int k = 0; k < c; ++k) {
            int gp = gb + k;
            if (gp < CAP) dstp[gp] = rec[ls + k];
        }
    }
}

__global__ void k_prep(const float* __restrict__ x, const int* __restrict__ deg,
                       float* __restrict__ dinv, float* __restrict__ xp) {
    int n = blockIdx.x * blockDim.x + threadIdx.x;
    if (n >= N_NODES) return;
    float di = rsqrtf((float)(deg[n] + 1));    // +1 self-loop
    dinv[n] = di;
    float4 v = reinterpret_cast<const float4*>(x)[n];
    v.x *= di; v.y *= di; v.z *= di; v.w *= di;
    reinterpret_cast<float4*>(xp)[n] = v;
}

// L1: per-bucket LDS aggregation of xp (4 feat) + fused dense1 (relu(@W1+b1))@W2
__global__ __launch_bounds__(256) void k_l1f(
    const float* __restrict__ xp, const float* __restrict__ dinv,
    const unsigned* __restrict__ pay, const int* __restrict__ bcnt,
    const float* __restrict__ W1, const float* __restrict__ b1,
    const float* __restrict__ W2, float* __restrict__ t2p) {
    __shared__ float sW1[256], sb1[64], sW2[2048], tile[NPB * 4];
    int tid = threadIdx.x;
    sW1[tid] = W1[tid];
    if (tid < 64) sb1[tid] = b1[tid];
    for (int i = tid; i < 2048; i += 256) sW2[i] = W2[i];
    for (int i = tid; i < NPB * 4; i += 256) tile[i] = 0.0f;
    __syncthreads();

    int b = blockIdx.x;
    int cnt = bcnt[b]; if (cnt > CAP) cnt = CAP;
    const unsigned* P = pay + (size_t)b * CAP;
    int f = tid & 3, g = tid >> 2;                       // 64 edges / iter
#pragma unroll 4
    for (int e = g; e < cnt; e += 64) {
        unsigned w = P[e];
        int s = w & 0x1FFFF, ld = w >> 17;
        atomicAdd(&tile[ld * 4 + f], xp[s * 4 + f]);
    }
    __syncthreads();

    int n = b * NPB + tid;
    if (tid < NPB && n < N_NODES) {
        float di = dinv[n];
        const float4 sv = reinterpret_cast<const float4*>(xp)[n];  // self term
        float a[4];
        a[0] = (tile[tid * 4 + 0] + sv.x) * di;
        a[1] = (tile[tid * 4 + 1] + sv.y) * di;
        a[2] = (tile[tid * 4 + 2] + sv.z) * di;
        a[3] = (tile[tid * 4 + 3] + sv.w) * di;
        float t[32];
#pragma unroll
        for (int k = 0; k < 32; ++k) t[k] = 0.0f;
        for (int j = 0; j < 64; ++j) {
            float h = sb1[j];
#pragma unroll
            for (int i = 0; i < 4; ++i) h += a[i] * sW1[i * 64 + j];
            h = fmaxf(h, 0.0f);                          // relu(L1)
#pragma unroll
            for (int k = 0; k < 32; ++k) t[k] += h * sW2[j * 32 + k];
        }
        float4* o = reinterpret_cast<float4*>(t2p + (size_t)n * 32);
#pragma unroll
        for (int q = 0; q < 8; ++q)
            o[q] = make_float4(t[q*4+0]*di, t[q*4+1]*di, t[q*4+2]*di, t[q*4+3]*di);
    }
}

// L2: per-bucket LDS aggregation of t2p (32 feat, 128B/edge) + fused dense2
__global__ __launch_bounds__(256) void k_l2f(
    const float* __restrict__ t2p, const float* __restrict__ dinv,
    const unsigned* __restrict__ pay, const int* __restrict__ bcnt,
    const float* __restrict__ b2, const float* __restrict__ W3,
    float* __restrict__ t3p) {
    __shared__ float sb2[32], sW3[512], tile[NPB * 32];
    int tid = threadIdx.x;
    if (tid < 32) sb2[tid] = b2[tid];
    for (int i = tid; i < 512; i += 256) sW3[i] = W3[i];
    for (int i = tid; i < NPB * 32; i += 256) tile[i] = 0.0f;
    __syncthreads();

    int b = blockIdx.x;
    int cnt = bcnt[b]; if (cnt > CAP) cnt = CAP;
    const unsigned* P = pay + (size_t)b * CAP;
    int f = tid & 31, g = tid >> 5;                      // 8 edges / iter
#pragma unroll 4
    for (int e = g; e < cnt; e += 8) {
        unsigned w = P[e];
        int s = w & 0x1FFFF, ld = w >> 17;
        atomicAdd(&tile[ld * 32 + f], t2p[(size_t)s * 32 + f]);
    }
    __syncthreads();

    int n = b * NPB + tid;
    if (tid < NPB && n < N_NODES) {
        float di = dinv[n];
        const float4* selfp = reinterpret_cast<const float4*>(t2p + (size_t)n * 32);
        float h[32];
#pragma unroll
        for (int q = 0; q < 8; ++q) {
            float4 sv = selfp[q];
            h[q*4+0] = fmaxf((tile[tid*32 + q*4+0] + sv.x) * di + sb2[q*4+0], 0.0f);
            h[q*4+1] = fmaxf((tile[tid*32 + q*4+1] + sv.y) * di + sb2[q*4+1], 0.0f);
            h[q*4+2] = fmaxf((tile[tid*32 + q*4+2] + sv.z) * di + sb2[q*4+2], 0.0f);
            h[q*4+3] = fmaxf((tile[tid*32 + q*4+3] + sv.w) * di + sb2[q*4+3], 0.0f);
        }
        float t[16];
#pragma unroll
        for (int k = 0; k < 16; ++k) t[k] = 0.0f;
        for (int j = 0; j < 32; ++j) {
#pragma unroll
            for (int k = 0; k < 16; ++k) t[k] += h[j] * sW3[j * 16 + k];
        }
        float4* o = reinterpret_cast<float4*>(t3p + (size_t)n * 16);
#pragma unroll
        for (int q = 0; q < 4; ++q)
            o[q] = make_float4(t[q*4+0]*di, t[q*4+1]*di, t[q*4+2]*di, t[q*4+3]*di);
    }
}

// L3: per-bucket LDS aggregation of t3p (16 feat, 64B/edge) + fused head dot + pool
__global__ __launch_bounds__(256) void k_l3f(
    const float* __restrict__ t3p, const float* __restrict__ dinv,
    const unsigned* __restrict__ pay, const int* __restrict__ bcnt,
    const float* __restrict__ b3, const float* __restrict__ Wl,
    const int* __restrict__ batch,
    float* __restrict__ gsum, int* __restrict__ gcnt) {
    __shared__ float sb3[16], sWl[16], tile[NPB * 16];
    int tid = threadIdx.x;
    if (tid < 16) { sb3[tid] = b3[tid]; sWl[tid] = Wl[tid]; }
    for (int i = tid; i < NPB * 16; i += 256) tile[i] = 0.0f;
    __syncthreads();

    int b = blockIdx.x;
    int cnt = bcnt[b]; if (cnt > CAP) cnt = CAP;
    const unsigned* P = pay + (size_t)b * CAP;
    int f = tid & 15, g = tid >> 4;                      // 16 edges / iter
#pragma unroll 4
    for (int e = g; e < cnt; e += 16) {
        unsigned w = P[e];
        int s = w & 0x1FFFF, ld = w >> 17;
        atomicAdd(&tile[ld * 16 + f], t3p[(size_t)s * 16 + f]);
    }
    __syncthreads();

    int n = b * NPB + tid;
    if (tid < NPB && n < N_NODES) {
        float di = dinv[n];
        const float4* selfp = reinterpret_cast<const float4*>(t3p + (size_t)n * 16);
        float s = 0.0f;
#pragma unroll
        for (int q = 0; q < 4; ++q) {
            float4 sv = selfp[q];
            s += ((tile[tid*16 + q*4+0] + sv.x) * di + sb3[q*4+0]) * sWl[q*4+0];
            s += ((tile[tid*16 + q*4+1] + sv.y) * di + sb3[q*4+1]) * sWl[q*4+1];
            s += ((tile[tid*16 + q*4+2] + sv.z) * di + sb3[q*4+2]) * sWl[q*4+2];
            s += ((tile[tid*16 + q*4+3] + sv.w) * di + sb3[q*4+3]) * sWl[q*4+3];
        }
        int gg = batch[n];
        atomicAdd(&gsum[gg], s);
        atomicAdd(&gcnt[gg], 1);
    }
}

__global__ void k_head(const float* __restrict__ gsum, const int* __restrict__ gcnt,
                       const float* __restrict__ bl, float* __restrict__ out) {
    int g = blockIdx.x * blockDim.x + threadIdx.x;
    if (g >= N_GRAPHS) return;
    float c = fmaxf((float)gcnt[g], 1.0f);
    out[g] = fmaxf(gsum[g] / c + bl[0], 0.0f);
}

extern "C" void kernel_launch(void* const* d_in, const int* in_sizes, int n_in,
                              void* d_out, int out_size, void* d_ws, size_t ws_size,
                              hipStream_t stream) {
    const float* x  = (const float*)d_in[0];
    const float* W1 = (const float*)d_in[1];
    const float* b1 = (const float*)d_in[2];
    const float* W2 = (const float*)d_in[3];
    const float* b2 = (const float*)d_in[4];
    const float* W3 = (const float*)d_in[5];
    const float* b3 = (const float*)d_in[6];
    const float* Wl = (const float*)d_in[7];
    const float* bl = (const float*)d_in[8];
    const int*   ei = (const int*)d_in[9];        // [2, E] row-major
    const int* batch = (const int*)d_in[10];
    const int* src = ei;
    const int* dst = ei + N_EDGES;
    float* out = (float*)d_out;

    const size_t N = N_NODES, G = N_GRAPHS;
    char* ws = (char*)d_ws;
    int*      deg  = (int*)     (ws);
    float*    dinv = (float*)   (ws + 4 * (N));
    float*    xp   = (float*)   (ws + 4 * (2 * N));
    float*    t2p  = (float*)   (ws + 4 * (6 * N));
    float*    t3p  = (float*)   (ws + 4 * (38 * N));
    int*      bcnt = (int*)     (ws + 4 * (54 * N));
    float*    gsum = (float*)   (ws + 4 * (54 * N + NB));
    int*      gcnt = (int*)     (ws + 4 * (54 * N + NB + G));
    unsigned* pay  = (unsigned*)(ws + 4 * (54 * N + NB + 2 * G));

    const int B = 256;
    const int gN = (N_NODES + B - 1) / B;            // 391
    const int gB = (N_EDGES + EPB - 1) / EPB;        // 782

    k_zero  <<<gN, B, 0, stream>>>(deg, bcnt, gsum, gcnt);
    k_bucket<<<gB, B, 0, stream>>>(src, dst, deg, bcnt, pay);
    k_prep  <<<gN, B, 0, stream>>>(x, deg, dinv, xp);
    k_l1f   <<<NB, B, 0, stream>>>(xp, dinv, pay, bcnt, W1, b1, W2, t2p);
    k_l2f   <<<NB, B, 0, stream>>>(t2p, dinv, pay, bcnt, b2, W3, t3p);
    k_l3f   <<<NB, B, 0, stream>>>(t3p, dinv, pay, bcnt, b3, Wl, batch, gsum, gcnt);
    k_head  <<<(N_GRAPHS + B - 1) / B, B, 0, stream>>>(gsum, gcnt, bl, out);
}